// Round 4
// baseline (375.432 us; speedup 1.0000x reference)
//
#include <hip/hip_runtime.h>
#include <hip/hip_bf16.h>

#define NB 256   // nodes
#define HH 64    // hidden

using short8 = __attribute__((ext_vector_type(8))) short;
using f4     = __attribute__((ext_vector_type(4))) float;

__device__ __forceinline__ float bf2f(__hip_bfloat16 v) { return __bfloat162float(v); }
__device__ __forceinline__ unsigned short f2bfbits(float f) {
    __hip_bfloat16 h = __float2bfloat16(f);
    return __builtin_bit_cast(unsigned short, h);
}
__device__ __forceinline__ float bits2f(unsigned short u) {
    return bf2f(__builtin_bit_cast(__hip_bfloat16, u));
}
// f32 -> (hi, lo) bf16 split fragments: v ~= hi + lo with |v - hi - lo| ~ 2^-18 |v|
__device__ __forceinline__ void cvtfrag2(const float* p, short8& hi, short8& lo) {
    float4 x = *reinterpret_cast<const float4*>(p);
    float4 y = *reinterpret_cast<const float4*>(p + 4);
    float v[8] = {x.x, x.y, x.z, x.w, y.x, y.y, y.z, y.w};
    #pragma unroll
    for (int i = 0; i < 8; ++i) {
        unsigned short h = f2bfbits(v[i]);
        hi[i] = (short)h;
        lo[i] = (short)f2bfbits(v[i] - bits2f(h));
    }
}

// ---- w3 column sums: the s-path needs only colsum_h(W3[l]) ----
__global__ void w3sum_kernel(const float* __restrict__ W3, float* __restrict__ w3s) {
    const int t = threadIdx.x;           // 128 threads: l = t>>6, k = t&63
    const int l = t >> 6, k = t & 63;
    float s = 0.f;
    for (int h = 0; h < 64; ++h) s += W3[(size_t)(l*64 + h)*64 + k];
    w3s[t] = s;
}

// ---- per-layer prep: s[b,i], Xj = X@W5^T, Xres = X@W6^T (all f32 VALU) ----
__global__ __launch_bounds__(256)
void prep_kernel(const float* __restrict__ Xsrc,
                 const float* __restrict__ w3s,      // 64 floats, this layer
                 const float* __restrict__ W5l,
                 const float* __restrict__ W6l,
                 float* __restrict__ s_ws,
                 float* __restrict__ Xj_ws,
                 float* __restrict__ Xres_ws)
{
    const int r = blockIdx.x * 4 + (threadIdx.x >> 6);   // row 0..2047 (= b*256+i)
    const int lane = threadIdx.x & 63;                   // = h
    float xr[64];
    #pragma unroll
    for (int k = 0; k < 16; ++k) {
        float4 v = *reinterpret_cast<const float4*>(Xsrc + (size_t)r*64 + k*4);
        xr[k*4+0] = v.x; xr[k*4+1] = v.y; xr[k*4+2] = v.z; xr[k*4+3] = v.w;
    }
    float aj = 0.f, ar = 0.f;
    #pragma unroll
    for (int k = 0; k < 64; ++k) {
        aj += xr[k] * W5l[lane*64 + k];
        ar += xr[k] * W6l[lane*64 + k];
    }
    Xj_ws[(size_t)r*64 + lane]   = aj;
    Xres_ws[(size_t)r*64 + lane] = ar;
    float sv = xr[lane] * w3s[lane];
    #pragma unroll
    for (int d = 1; d < 64; d <<= 1) sv += __shfl_xor(sv, d, 64);
    if (lane == 0) s_ws[r] = sv;
}

// ---- fused layer: E-GEMM (split-bf16 MFMA, ~f32-exact) + softmax + scale
//      + LN(E) + agg + X update ----
// One block per (b,i). D[h][j] = sum_k W4[h][k]*E[j][k]; A=W4, B=E^T.
// 16x16x32 bf16 MFMA: A[m=lane&15][k=quad*8+idx], B[k=quad*8+idx][n=lane&15],
// C/D: col(n)=lane&15, row(m)=quad*4+reg.
// Ein/Eout may alias (in-place, block-owned slice, reads precede writes):
// no __restrict__ on them. EOUT: 0 = none, 1 = f32 store.
template<int EOUT>
__global__ __launch_bounds__(256)
void layer_kernel(const float* Ein,
                  float* Eout,
                  const float* __restrict__ s_ws,
                  const float* __restrict__ Xj_ws,
                  const float* __restrict__ Xres_ws,
                  const float* __restrict__ Xold,
                  float* __restrict__ Xnext,
                  const float* __restrict__ W4l,
                  const float* __restrict__ eg,
                  const float* __restrict__ eb,
                  const float* __restrict__ ng,
                  const float* __restrict__ nb)
{
    __shared__ float att[NB];
    __shared__ float red[8];
    __shared__ float agg_lds[4][64];

    const int bi  = blockIdx.x;          // b*256 + i
    const int b   = bi >> 8;
    const int tid = threadIdx.x;
    const int w   = tid >> 6;            // wave 0..3 -> j in [w*64, w*64+64)
    const int lane = tid & 63;
    const int m = lane & 15;
    const int q = lane >> 4;

    const size_t ebase = (size_t)bi * (NB * HH);

    // A fragments: W4 rows, hi/lo split (L2-hot, 16 KB)
    short8 aH[4][2], aL[4][2];
    #pragma unroll
    for (int mt = 0; mt < 4; ++mt)
        #pragma unroll
        for (int ks = 0; ks < 2; ++ks)
            cvtfrag2(W4l + (size_t)(mt*16 + m)*64 + ks*32 + q*8, aH[mt][ks], aL[mt][ks]);

    f4 acc[4][4] = {};   // [mt(h-tile)][jt(j-tile)]

    #pragma unroll
    for (int jt = 0; jt < 4; ++jt) {
        const int jj = w*64 + jt*16 + m;
        const float* er = Ein + ebase + (size_t)jj * 64;
        short8 bh0, bl0, bh1, bl1;
        cvtfrag2(er + q*8,      bh0, bl0);
        cvtfrag2(er + 32 + q*8, bh1, bl1);
        #pragma unroll
        for (int mt = 0; mt < 4; ++mt) {
            acc[mt][jt] = __builtin_amdgcn_mfma_f32_16x16x32_bf16(aH[mt][0], bh0, acc[mt][jt], 0, 0, 0);
            acc[mt][jt] = __builtin_amdgcn_mfma_f32_16x16x32_bf16(aL[mt][0], bh0, acc[mt][jt], 0, 0, 0);
            acc[mt][jt] = __builtin_amdgcn_mfma_f32_16x16x32_bf16(aH[mt][0], bl0, acc[mt][jt], 0, 0, 0);
            acc[mt][jt] = __builtin_amdgcn_mfma_f32_16x16x32_bf16(aH[mt][1], bh1, acc[mt][jt], 0, 0, 0);
            acc[mt][jt] = __builtin_amdgcn_mfma_f32_16x16x32_bf16(aL[mt][1], bh1, acc[mt][jt], 0, 0, 0);
            acc[mt][jt] = __builtin_amdgcn_mfma_f32_16x16x32_bf16(aH[mt][1], bl1, acc[mt][jt], 0, 0, 0);
        }
    }

    // t_j = sum_h E_hat[j][h] (rowsum of the GEMM) -> att buffer
    #pragma unroll
    for (int jt = 0; jt < 4; ++jt) {
        float t = 0.f;
        #pragma unroll
        for (int mt = 0; mt < 4; ++mt)
            #pragma unroll
            for (int r = 0; r < 4; ++r) t += acc[mt][jt][r];
        t += __shfl_xor(t, 16, 64);
        t += __shfl_xor(t, 32, 64);
        if (lane < 16) att[w*64 + jt*16 + lane] = t;
    }
    __syncthreads();

    // block softmax over j (tid = j): logits = s_i + s_j + t_j
    const float si = s_ws[bi];
    const float lj = att[tid] + si + s_ws[b*NB + tid];
    float mx = lj;
    #pragma unroll
    for (int d = 1; d < 64; d <<= 1) mx = fmaxf(mx, __shfl_xor(mx, d, 64));
    if (lane == 0) red[w] = mx;
    __syncthreads();
    mx = fmaxf(fmaxf(red[0], red[1]), fmaxf(red[2], red[3]));
    const float ev = __expf(lj - mx);
    float sm = ev;
    #pragma unroll
    for (int d = 1; d < 64; d <<= 1) sm += __shfl_xor(sm, d, 64);
    if (lane == 0) red[4 + w] = sm;
    __syncthreads();
    sm = (red[4] + red[5]) + (red[6] + red[7]);
    att[tid] = ev / sm;
    __syncthreads();

    // scale E_hat -> E_next
    float attv[4];
    #pragma unroll
    for (int jt = 0; jt < 4; ++jt) attv[jt] = att[w*64 + jt*16 + m];
    #pragma unroll
    for (int mt = 0; mt < 4; ++mt)
        #pragma unroll
        for (int jt = 0; jt < 4; ++jt)
            #pragma unroll
            for (int r = 0; r < 4; ++r) acc[mt][jt][r] *= attv[jt];

    // per-row LN stats (over h) for E_next
    float mean[4], rstd[4];
    #pragma unroll
    for (int jt = 0; jt < 4; ++jt) {
        float s = 0.f, ss = 0.f;
        #pragma unroll
        for (int mt = 0; mt < 4; ++mt)
            #pragma unroll
            for (int r = 0; r < 4; ++r) { float v = acc[mt][jt][r]; s += v; ss += v*v; }
        s  += __shfl_xor(s, 16, 64);  s  += __shfl_xor(s, 32, 64);
        ss += __shfl_xor(ss, 16, 64); ss += __shfl_xor(ss, 32, 64);
        float mu = s * (1.f/64.f);
        mean[jt] = mu;
        rstd[jt] = rsqrtf(ss * (1.f/64.f) - mu*mu + 1e-5f);
    }

    // agg[h] partials: sum_j E_next[j][h] * Xj[b,j,h] (Xj L2-hot, 64 KB per b)
    float p[4][4] = {};
    #pragma unroll
    for (int jt = 0; jt < 4; ++jt) {
        const int jj = w*64 + jt*16 + m;
        const float* xb = Xj_ws + (size_t)(b*NB + jj) * 64;
        #pragma unroll
        for (int mt = 0; mt < 4; ++mt) {
            float4 xv = *reinterpret_cast<const float4*>(xb + mt*16 + q*4);
            p[mt][0] += acc[mt][jt][0] * xv.x;
            p[mt][1] += acc[mt][jt][1] * xv.y;
            p[mt][2] += acc[mt][jt][2] * xv.z;
            p[mt][3] += acc[mt][jt][3] * xv.w;
        }
    }
    #pragma unroll
    for (int d = 1; d < 16; d <<= 1)
        #pragma unroll
        for (int mt = 0; mt < 4; ++mt)
            #pragma unroll
            for (int r = 0; r < 4; ++r) p[mt][r] += __shfl_xor(p[mt][r], d, 64);
    if (m == 0) {
        #pragma unroll
        for (int mt = 0; mt < 4; ++mt) {
            float4 st = make_float4(p[mt][0], p[mt][1], p[mt][2], p[mt][3]);
            *reinterpret_cast<float4*>(&agg_lds[w][mt*16 + q*4]) = st;
        }
    }

    // E_out = LN(E_next)*eg+eb, f32 (skipped in last layer: unused by head)
    if constexpr (EOUT != 0) {
        float egv[4][4], ebv[4][4];
        #pragma unroll
        for (int mt = 0; mt < 4; ++mt)
            #pragma unroll
            for (int r = 0; r < 4; ++r) {
                const int h = mt*16 + q*4 + r;
                egv[mt][r] = eg[h];
                ebv[mt][r] = eb[h];
            }
        #pragma unroll
        for (int jt = 0; jt < 4; ++jt) {
            const int jj = w*64 + jt*16 + m;
            float* eo = Eout + ebase + (size_t)jj * 64;
            #pragma unroll
            for (int mt = 0; mt < 4; ++mt) {
                float4 st;
                st.x = (acc[mt][jt][0] - mean[jt]) * rstd[jt] * egv[mt][0] + ebv[mt][0];
                st.y = (acc[mt][jt][1] - mean[jt]) * rstd[jt] * egv[mt][1] + ebv[mt][1];
                st.z = (acc[mt][jt][2] - mean[jt]) * rstd[jt] * egv[mt][2] + ebv[mt][2];
                st.w = (acc[mt][jt][3] - mean[jt]) * rstd[jt] * egv[mt][3] + ebv[mt][3];
                *reinterpret_cast<float4*>(eo + mt*16 + q*4) = st;
            }
        }
    }
    __syncthreads();

    // X update: X = LN(relu(agg + Xres))*ng+nb + X_old  (wave 0, lane = h)
    if (w == 0) {
        float a = agg_lds[0][lane] + agg_lds[1][lane] + agg_lds[2][lane] + agg_lds[3][lane];
        float v = fmaxf(a + Xres_ws[(size_t)bi*64 + lane], 0.f);
        float s = v, ss = v*v;
        #pragma unroll
        for (int d = 1; d < 64; d <<= 1) { s += __shfl_xor(s, d, 64); ss += __shfl_xor(ss, d, 64); }
        float mu  = s * (1.f/64.f);
        float var = ss * (1.f/64.f) - mu*mu;
        Xnext[(size_t)bi*64 + lane] =
            (v - mu) * rsqrtf(var + 1e-5f) * ng[lane] + nb[lane] + Xold[(size_t)bi*64 + lane];
    }
}

// ---- head: out = relu(X@hw1^T + hb1) @ hw2^T + hb2  (f32 output!) ----
__global__ __launch_bounds__(256)
void head_kernel(const float* __restrict__ Xf,
                 const float* __restrict__ hw1,
                 const float* __restrict__ hb1,
                 const float* __restrict__ hw2,
                 const float* __restrict__ hb2,
                 float* __restrict__ out)
{
    __shared__ float h1s[4][64];
    const int w = threadIdx.x >> 6;
    const int r = blockIdx.x * 4 + w;
    const int lane = threadIdx.x & 63;
    float xr[64];
    #pragma unroll
    for (int k = 0; k < 16; ++k) {
        float4 v = *reinterpret_cast<const float4*>(Xf + (size_t)r*64 + k*4);
        xr[k*4+0] = v.x; xr[k*4+1] = v.y; xr[k*4+2] = v.z; xr[k*4+3] = v.w;
    }
    float a = hb1[lane];
    #pragma unroll
    for (int k = 0; k < 64; ++k) a += xr[k] * hw1[lane*64 + k];
    h1s[w][lane] = fmaxf(a, 0.f);
    __syncthreads();
    if (lane < 10) {
        float o = hb2[lane];
        #pragma unroll
        for (int h = 0; h < 64; ++h) o += h1s[w][h] * hw2[lane*64 + h];
        out[(size_t)r*10 + lane] = o;
    }
}

extern "C" void kernel_launch(void* const* d_in, const int* in_sizes, int n_in,
                              void* d_out, int out_size, void* d_ws, size_t ws_size,
                              hipStream_t stream) {
    const float* X   = (const float*)d_in[0];
    float*       E   = (float*)d_in[1];          // layer-0 LN(E) written in place
    const float* W3  = (const float*)d_in[2];
    const float* W4  = (const float*)d_in[3];
    const float* W5  = (const float*)d_in[4];
    const float* W6  = (const float*)d_in[5];
    const float* ng  = (const float*)d_in[6];
    const float* nbp = (const float*)d_in[7];
    const float* eg  = (const float*)d_in[8];
    const float* ebp = (const float*)d_in[9];
    const float* hw1 = (const float*)d_in[10];
    const float* hb1 = (const float*)d_in[11];
    const float* hw2 = (const float*)d_in[12];
    const float* hb2 = (const float*)d_in[13];
    float* outp = (float*)d_out;

    float* wsf   = (float*)d_ws;
    float* s_ws  = wsf;                  // 2048
    float* Xj    = s_ws + 2048;          // 131072
    float* Xres  = Xj + 131072;          // 131072
    float* Xa    = Xres + 131072;        // 131072
    float* Xb    = Xa + 131072;          // 131072
    float* w3s   = Xb + 131072;          // 128

    w3sum_kernel<<<1, 128, 0, stream>>>(W3, w3s);

    // layer 0: E_out = LN(E_next) written f32 in place over d_in[1]
    prep_kernel<<<512, 256, 0, stream>>>(X, w3s, W5, W6, s_ws, Xj, Xres);
    layer_kernel<1><<<2048, 256, 0, stream>>>(E, E, s_ws, Xj, Xres,
        X, Xa, W4, eg, ebp, ng, nbp);

    // layer 1: E output unused by the head -> skip LN(E) + store
    prep_kernel<<<512, 256, 0, stream>>>(Xa, w3s + 64, W5 + 4096, W6 + 4096,
        s_ws, Xj, Xres);
    layer_kernel<0><<<2048, 256, 0, stream>>>(E, nullptr, s_ws, Xj, Xres,
        Xa, Xb, W4 + 4096, eg + 64, ebp + 64, ng + 64, nbp + 64);

    head_kernel<<<512, 256, 0, stream>>>(Xb, hw1, hb1, hw2, hb2, outp);
}

// Round 5
// 309.418 us; speedup vs baseline: 1.2133x; 1.2133x over previous
//
#include <hip/hip_runtime.h>
#include <hip/hip_bf16.h>

#define NB 256   // nodes
#define HH 64    // hidden

using short8 = __attribute__((ext_vector_type(8))) short;
using f4     = __attribute__((ext_vector_type(4))) float;

static __device__ __forceinline__ unsigned short f2bfbits(float f) {
    __hip_bfloat16 h = __float2bfloat16(f);
    return __builtin_bit_cast(unsigned short, h);
}

// split 8 f32 -> hi (bit-truncated bf16) + lo (RNE residual bf16); v = hi+lo to ~2^-17
static __device__ __forceinline__ void split8(const float* v, short8& hi, short8& lo) {
    unsigned int hd[4], ld[4];
    #pragma unroll
    for (int j = 0; j < 4; ++j) {
        unsigned int u0 = __builtin_bit_cast(unsigned int, v[2*j]);
        unsigned int u1 = __builtin_bit_cast(unsigned int, v[2*j+1]);
        hd[j] = (u1 & 0xFFFF0000u) | (u0 >> 16);
        float r0 = v[2*j]   - __builtin_bit_cast(float, u0 & 0xFFFF0000u);
        float r1 = v[2*j+1] - __builtin_bit_cast(float, u1 & 0xFFFF0000u);
        ld[j] = ((unsigned int)f2bfbits(r1) << 16) | (unsigned int)f2bfbits(r0);
    }
    uint4 h4; h4.x = hd[0]; h4.y = hd[1]; h4.z = hd[2]; h4.w = hd[3];
    uint4 l4; l4.x = ld[0]; l4.y = ld[1]; l4.z = ld[2]; l4.w = ld[3];
    hi = __builtin_bit_cast(short8, h4);
    lo = __builtin_bit_cast(short8, l4);
}

// load an L1 B-fragment: two ushort4 entries 128 B apart -> short8
static __device__ __forceinline__ short8 ld_frag_pair(const char* base, int idx0) {
    uint2 a = *reinterpret_cast<const uint2*>(base + (size_t)idx0 * 8);
    uint2 b = *reinterpret_cast<const uint2*>(base + (size_t)idx0 * 8 + 128);
    uint4 u; u.x = a.x; u.y = a.y; u.z = b.x; u.w = b.y;
    return __builtin_bit_cast(short8, u);
}

// ---- setup: block 0 = W3 colsums; blocks 1,2 = W4 fragment tables (bf16 hi/lo) ----
// Table layout per layer: entry uint4 (=short8 frag) at [(mt*4+f)*64 + lane],
// f: 0=hi ks0, 1=hi ks1, 2=lo ks0, 3=lo ks1.
__global__ __launch_bounds__(256)
void setup_kernel(const float* __restrict__ W3, const float* __restrict__ W4,
                  float* __restrict__ w3s, uint4* __restrict__ w4tab) {
    const int t = threadIdx.x;
    if (blockIdx.x == 0) {
        if (t < 128) {
            const int l = t >> 6, k = t & 63;
            float s = 0.f;
            for (int h = 0; h < 64; ++h) s += W3[(size_t)(l*64 + h)*64 + k];
            w3s[t] = s;
        }
    } else {
        const int l = blockIdx.x - 1;
        const float* W4l = W4 + (size_t)l * 4096;
        uint4* tab = w4tab + (size_t)l * 1024;
        const int mt = t >> 6, lane = t & 63, m = lane & 15, q = lane >> 4;
        const float* row = W4l + (size_t)(mt*16 + m) * 64;
        #pragma unroll
        for (int ks = 0; ks < 2; ++ks) {
            float v[8];
            *reinterpret_cast<float4*>(&v[0]) = *reinterpret_cast<const float4*>(row + ks*32 + q*8);
            *reinterpret_cast<float4*>(&v[4]) = *reinterpret_cast<const float4*>(row + ks*32 + q*8 + 4);
            short8 hi, lo;
            split8(v, hi, lo);
            tab[(mt*4 + ks)*64 + lane]     = __builtin_bit_cast(uint4, hi);
            tab[(mt*4 + 2 + ks)*64 + lane] = __builtin_bit_cast(uint4, lo);
        }
    }
}

// ---- prep: s[b,i], Xj (fragment-native), Xres. W5/W6 staged in LDS ----
__global__ __launch_bounds__(256)
void prep_kernel(const float* __restrict__ Xsrc,
                 const float* __restrict__ w3s,
                 const float* __restrict__ W5l,
                 const float* __restrict__ W6l,
                 float* __restrict__ s_ws,
                 float* __restrict__ Xjf,
                 float* __restrict__ Xres_ws)
{
    __shared__ float w5s[64*65];
    __shared__ float w6s[64*65];
    const int t = threadIdx.x;
    #pragma unroll
    for (int j = 0; j < 4; ++j) {
        const int fidx = j*1024 + t*4;
        float4 v5 = *reinterpret_cast<const float4*>(W5l + fidx);
        float4 v6 = *reinterpret_cast<const float4*>(W6l + fidx);
        const int row = fidx >> 6, col = fidx & 63;
        w5s[row*65+col+0] = v5.x; w5s[row*65+col+1] = v5.y;
        w5s[row*65+col+2] = v5.z; w5s[row*65+col+3] = v5.w;
        w6s[row*65+col+0] = v6.x; w6s[row*65+col+1] = v6.y;
        w6s[row*65+col+2] = v6.z; w6s[row*65+col+3] = v6.w;
    }
    __syncthreads();

    const int w = t >> 6, lane = t & 63;
    const int r = blockIdx.x * 4 + w;                 // b*256 + i
    float xr[64];
    #pragma unroll
    for (int k = 0; k < 16; ++k) {
        float4 v = *reinterpret_cast<const float4*>(Xsrc + (size_t)r*64 + k*4);
        xr[k*4+0] = v.x; xr[k*4+1] = v.y; xr[k*4+2] = v.z; xr[k*4+3] = v.w;
    }
    float aj = 0.f, ar = 0.f;
    #pragma unroll
    for (int k = 0; k < 64; ++k) {
        aj += xr[k] * w5s[lane*65 + k];
        ar += xr[k] * w6s[lane*65 + k];
    }
    // Xj store in fragment-native layout: [b][w][jt][mt][q*16+m] float4(ri)
    const int b = r >> 8, j = r & 255;
    const int wj = j >> 6, jt = (j >> 4) & 3, m = j & 15;
    const int mt = lane >> 4, q = (lane >> 2) & 3, ri = lane & 3;
    Xjf[(size_t)b*16384 + (size_t)(((wj*4 + jt)*4 + mt)*64 + (q*16 + m))*4 + ri] = aj;
    Xres_ws[(size_t)r*64 + lane] = ar;
    float sv = xr[lane] * w3s[lane];
    #pragma unroll
    for (int d = 1; d < 64; d <<= 1) sv += __shfl_xor(sv, d, 64);
    if (lane == 0) s_ws[r] = sv;
}

// ---- fused layer ----
// One block per (b,i). D[h][j] = sum_k W4[h][k]*E[j][k]; A=W4 (table), B=E.
// FIRST: B from f32 rows of Ebuf (input E), epilogue writes LN(E_next) as bf16
//        hi/lo planes IN PLACE over the block's own 64-KB slice of Ebuf
//        (all reads drain at the pre-store __syncthreads -> hazard-free).
// !FIRST: B loaded directly from the hi/lo planes (zero conversion VALU).
template<bool FIRST>
__global__ __launch_bounds__(256)
void layer_kernel(void* Ebuf,
                  const float* __restrict__ s_ws,
                  const float* __restrict__ Xjf,
                  const float* __restrict__ Xres_ws,
                  const float* __restrict__ Xold,
                  float* __restrict__ Xnext,
                  const uint4* __restrict__ w4tab,
                  const float* __restrict__ eg,
                  const float* __restrict__ eb,
                  const float* __restrict__ ng,
                  const float* __restrict__ nb)
{
    __shared__ float att[NB];
    __shared__ float red[8];
    __shared__ float agg_lds[4][64];

    const int bi  = blockIdx.x;          // b*256 + i
    const int b   = bi >> 8;
    const int tid = threadIdx.x;
    const int w   = tid >> 6;            // wave -> j in [w*64, w*64+64)
    const int lane = tid & 63;
    const int m = lane & 15;
    const int q = lane >> 4;

    char* ebase = (char*)Ebuf + (size_t)bi * 65536;

    // A fragments from the precomputed table (coalesced, L2-hot)
    short8 aH[4][2], aL[4][2];
    #pragma unroll
    for (int mt = 0; mt < 4; ++mt) {
        aH[mt][0] = __builtin_bit_cast(short8, w4tab[(mt*4 + 0)*64 + lane]);
        aH[mt][1] = __builtin_bit_cast(short8, w4tab[(mt*4 + 1)*64 + lane]);
        aL[mt][0] = __builtin_bit_cast(short8, w4tab[(mt*4 + 2)*64 + lane]);
        aL[mt][1] = __builtin_bit_cast(short8, w4tab[(mt*4 + 3)*64 + lane]);
    }

    f4 acc[4][4] = {};   // [mt][jt]

    #pragma unroll
    for (int jt = 0; jt < 4; ++jt) {
        short8 bh0, bl0, bh1, bl1;
        if constexpr (FIRST) {
            const float* er = (const float*)ebase + (size_t)(w*64 + jt*16 + m) * 64;
            float v0[8], v1[8];
            *reinterpret_cast<float4*>(&v0[0]) = *reinterpret_cast<const float4*>(er + q*8);
            *reinterpret_cast<float4*>(&v0[4]) = *reinterpret_cast<const float4*>(er + q*8 + 4);
            *reinterpret_cast<float4*>(&v1[0]) = *reinterpret_cast<const float4*>(er + 32 + q*8);
            *reinterpret_cast<float4*>(&v1[4]) = *reinterpret_cast<const float4*>(er + 32 + q*8 + 4);
            split8(v0, bh0, bl0);
            split8(v1, bh1, bl1);
        } else {
            const char* hiP = ebase;
            const char* loP = ebase + 32768;
            const int col = (q & 1)*32 + m;            // qa*16 + m, qa = 2*(q&1)
            const int base0 = ((w*4 + jt)*4)*64;
            const int mt0 = (q >> 1);
            bh0 = ld_frag_pair(hiP, base0 + mt0*64 + col);
            bh1 = ld_frag_pair(hiP, base0 + (2 + mt0)*64 + col);
            bl0 = ld_frag_pair(loP, base0 + mt0*64 + col);
            bl1 = ld_frag_pair(loP, base0 + (2 + mt0)*64 + col);
        }
        #pragma unroll
        for (int mt = 0; mt < 4; ++mt) {
            acc[mt][jt] = __builtin_amdgcn_mfma_f32_16x16x32_bf16(aH[mt][0], bh0, acc[mt][jt], 0, 0, 0);
            acc[mt][jt] = __builtin_amdgcn_mfma_f32_16x16x32_bf16(aL[mt][0], bh0, acc[mt][jt], 0, 0, 0);
            acc[mt][jt] = __builtin_amdgcn_mfma_f32_16x16x32_bf16(aH[mt][0], bl0, acc[mt][jt], 0, 0, 0);
            acc[mt][jt] = __builtin_amdgcn_mfma_f32_16x16x32_bf16(aH[mt][1], bh1, acc[mt][jt], 0, 0, 0);
            acc[mt][jt] = __builtin_amdgcn_mfma_f32_16x16x32_bf16(aL[mt][1], bh1, acc[mt][jt], 0, 0, 0);
            acc[mt][jt] = __builtin_amdgcn_mfma_f32_16x16x32_bf16(aH[mt][1], bl1, acc[mt][jt], 0, 0, 0);
        }
    }

    // t_j = rowsum of E_hat -> att buffer
    #pragma unroll
    for (int jt = 0; jt < 4; ++jt) {
        float t = 0.f;
        #pragma unroll
        for (int mt = 0; mt < 4; ++mt)
            #pragma unroll
            for (int r = 0; r < 4; ++r) t += acc[mt][jt][r];
        t += __shfl_xor(t, 16, 64);
        t += __shfl_xor(t, 32, 64);
        if (lane < 16) att[w*64 + jt*16 + lane] = t;
    }
    __syncthreads();

    // block softmax over j (tid = j)
    const float lj = att[tid] + s_ws[bi] + s_ws[b*NB + tid];
    float mx = lj;
    #pragma unroll
    for (int d = 1; d < 64; d <<= 1) mx = fmaxf(mx, __shfl_xor(mx, d, 64));
    if (lane == 0) red[w] = mx;
    __syncthreads();
    mx = fmaxf(fmaxf(red[0], red[1]), fmaxf(red[2], red[3]));
    const float ev = __expf(lj - mx);
    float sm = ev;
    #pragma unroll
    for (int d = 1; d < 64; d <<= 1) sm += __shfl_xor(sm, d, 64);
    if (lane == 0) red[4 + w] = sm;
    __syncthreads();
    sm = (red[4] + red[5]) + (red[6] + red[7]);
    att[tid] = ev / sm;
    __syncthreads();

    // scale E_hat -> E_next
    float attv[4];
    #pragma unroll
    for (int jt = 0; jt < 4; ++jt) attv[jt] = att[w*64 + jt*16 + m];
    #pragma unroll
    for (int mt = 0; mt < 4; ++mt)
        #pragma unroll
        for (int jt = 0; jt < 4; ++jt)
            #pragma unroll
            for (int r = 0; r < 4; ++r) acc[mt][jt][r] *= attv[jt];

    // per-row LN stats over h
    float mean[4], rstd[4];
    #pragma unroll
    for (int jt = 0; jt < 4; ++jt) {
        float s = 0.f, ss = 0.f;
        #pragma unroll
        for (int mt = 0; mt < 4; ++mt)
            #pragma unroll
            for (int r = 0; r < 4; ++r) { float v = acc[mt][jt][r]; s += v; ss += v*v; }
        s  += __shfl_xor(s, 16, 64);  s  += __shfl_xor(s, 32, 64);
        ss += __shfl_xor(ss, 16, 64); ss += __shfl_xor(ss, 32, 64);
        float mu = s * (1.f/64.f);
        mean[jt] = mu;
        rstd[jt] = rsqrtf(ss * (1.f/64.f) - mu*mu + 1e-5f);
    }

    // agg partials: sum_j E_next[j][h]*Xj[b,j,h]; Xj in fragment-native layout
    float p[4][4] = {};
    #pragma unroll
    for (int jt = 0; jt < 4; ++jt) {
        #pragma unroll
        for (int mt = 0; mt < 4; ++mt) {
            float4 xv = *reinterpret_cast<const float4*>(
                Xjf + (size_t)b*16384 + (size_t)(((w*4 + jt)*4 + mt)*64 + lane)*4);
            p[mt][0] += acc[mt][jt][0] * xv.x;
            p[mt][1] += acc[mt][jt][1] * xv.y;
            p[mt][2] += acc[mt][jt][2] * xv.z;
            p[mt][3] += acc[mt][jt][3] * xv.w;
        }
    }
    #pragma unroll
    for (int d = 1; d < 16; d <<= 1)
        #pragma unroll
        for (int mt = 0; mt < 4; ++mt)
            #pragma unroll
            for (int r = 0; r < 4; ++r) p[mt][r] += __shfl_xor(p[mt][r], d, 64);
    if (m == 0) {
        #pragma unroll
        for (int mt = 0; mt < 4; ++mt) {
            float4 st = make_float4(p[mt][0], p[mt][1], p[mt][2], p[mt][3]);
            *reinterpret_cast<float4*>(&agg_lds[w][mt*16 + q*4]) = st;
        }
    }

    // epilogue: LN(E_next) -> bf16 hi/lo planes, fragment-native (FIRST only)
    if constexpr (FIRST) {
        float egv[4][4], ebv[4][4];
        #pragma unroll
        for (int mt = 0; mt < 4; ++mt)
            #pragma unroll
            for (int r = 0; r < 4; ++r) {
                const int h = mt*16 + q*4 + r;
                egv[mt][r] = eg[h];
                ebv[mt][r] = eb[h];
            }
        char* hiP = ebase;
        char* loP = ebase + 32768;
        #pragma unroll
        for (int jt = 0; jt < 4; ++jt) {
            #pragma unroll
            for (int mt = 0; mt < 4; ++mt) {
                float o[4];
                #pragma unroll
                for (int r = 0; r < 4; ++r)
                    o[r] = (acc[mt][jt][r] - mean[jt]) * rstd[jt] * egv[mt][r] + ebv[mt][r];
                unsigned int u0 = __builtin_bit_cast(unsigned int, o[0]);
                unsigned int u1 = __builtin_bit_cast(unsigned int, o[1]);
                unsigned int u2 = __builtin_bit_cast(unsigned int, o[2]);
                unsigned int u3 = __builtin_bit_cast(unsigned int, o[3]);
                uint2 h2;
                h2.x = (u1 & 0xFFFF0000u) | (u0 >> 16);
                h2.y = (u3 & 0xFFFF0000u) | (u2 >> 16);
                float r0 = o[0] - __builtin_bit_cast(float, u0 & 0xFFFF0000u);
                float r1 = o[1] - __builtin_bit_cast(float, u1 & 0xFFFF0000u);
                float r2 = o[2] - __builtin_bit_cast(float, u2 & 0xFFFF0000u);
                float r3 = o[3] - __builtin_bit_cast(float, u3 & 0xFFFF0000u);
                uint2 l2;
                l2.x = ((unsigned int)f2bfbits(r1) << 16) | (unsigned int)f2bfbits(r0);
                l2.y = ((unsigned int)f2bfbits(r3) << 16) | (unsigned int)f2bfbits(r2);
                const int idxS = ((w*4 + jt)*4 + mt)*64 + lane;
                *reinterpret_cast<uint2*>(hiP + (size_t)idxS*8) = h2;
                *reinterpret_cast<uint2*>(loP + (size_t)idxS*8) = l2;
            }
        }
    }
    __syncthreads();

    // X update (wave 0, lane = h)
    if (w == 0) {
        float a = agg_lds[0][lane] + agg_lds[1][lane] + agg_lds[2][lane] + agg_lds[3][lane];
        float v = fmaxf(a + Xres_ws[(size_t)bi*64 + lane], 0.f);
        float s = v, ss = v*v;
        #pragma unroll
        for (int d = 1; d < 64; d <<= 1) { s += __shfl_xor(s, d, 64); ss += __shfl_xor(ss, d, 64); }
        float mu  = s * (1.f/64.f);
        float var = ss * (1.f/64.f) - mu*mu;
        Xnext[(size_t)bi*64 + lane] =
            (v - mu) * rsqrtf(var + 1e-5f) * ng[lane] + nb[lane] + Xold[(size_t)bi*64 + lane];
    }
}

// ---- head: out = relu(X@hw1^T + hb1) @ hw2^T + hb2 (f32 out), weights LDS-staged ----
__global__ __launch_bounds__(256)
void head_kernel(const float* __restrict__ Xf,
                 const float* __restrict__ hw1,
                 const float* __restrict__ hb1,
                 const float* __restrict__ hw2,
                 const float* __restrict__ hb2,
                 float* __restrict__ out)
{
    __shared__ float w1s[64*65];
    __shared__ float w2s[10*65];
    __shared__ float h1s[4][64];
    const int t = threadIdx.x;
    #pragma unroll
    for (int j = 0; j < 4; ++j) {
        const int fidx = j*1024 + t*4;
        float4 v = *reinterpret_cast<const float4*>(hw1 + fidx);
        const int row = fidx >> 6, col = fidx & 63;
        w1s[row*65+col+0] = v.x; w1s[row*65+col+1] = v.y;
        w1s[row*65+col+2] = v.z; w1s[row*65+col+3] = v.w;
    }
    if (t < 160) {
        const int fidx = t*4;
        float4 v = *reinterpret_cast<const float4*>(hw2 + fidx);
        const int row = fidx >> 6, col = fidx & 63;
        w2s[row*65+col+0] = v.x; w2s[row*65+col+1] = v.y;
        w2s[row*65+col+2] = v.z; w2s[row*65+col+3] = v.w;
    }
    __syncthreads();

    const int w = t >> 6, lane = t & 63;
    const int r = blockIdx.x * 4 + w;
    float xr[64];
    #pragma unroll
    for (int k = 0; k < 16; ++k) {
        float4 v = *reinterpret_cast<const float4*>(Xf + (size_t)r*64 + k*4);
        xr[k*4+0] = v.x; xr[k*4+1] = v.y; xr[k*4+2] = v.z; xr[k*4+3] = v.w;
    }
    float a = hb1[lane];
    #pragma unroll
    for (int k = 0; k < 64; ++k) a += xr[k] * w1s[lane*65 + k];
    h1s[w][lane] = fmaxf(a, 0.f);
    __syncthreads();
    if (lane < 10) {
        float o = hb2[lane];
        #pragma unroll
        for (int h = 0; h < 64; ++h) o += h1s[w][h] * w2s[lane*65 + h];
        out[(size_t)r*10 + lane] = o;
    }
}

extern "C" void kernel_launch(void* const* d_in, const int* in_sizes, int n_in,
                              void* d_out, int out_size, void* d_ws, size_t ws_size,
                              hipStream_t stream) {
    const float* X   = (const float*)d_in[0];
    void*        E   = (void*)d_in[1];           // f32 in; bf16 hi/lo planes written in place
    const float* W3  = (const float*)d_in[2];
    const float* W4  = (const float*)d_in[3];
    const float* W5  = (const float*)d_in[4];
    const float* W6  = (const float*)d_in[5];
    const float* ng  = (const float*)d_in[6];
    const float* nbp = (const float*)d_in[7];
    const float* eg  = (const float*)d_in[8];
    const float* ebp = (const float*)d_in[9];
    const float* hw1 = (const float*)d_in[10];
    const float* hb1 = (const float*)d_in[11];
    const float* hw2 = (const float*)d_in[12];
    const float* hb2 = (const float*)d_in[13];
    float* outp = (float*)d_out;

    float* wsf   = (float*)d_ws;
    float* s_ws  = wsf;                    // 2048
    float* Xjf   = wsf + 2048;             // 131072
    float* Xres  = wsf + 133120;           // 131072
    float* Xa    = wsf + 264192;           // 131072
    float* Xb    = wsf + 395264;           // 131072
    float* w3s   = wsf + 526336;           // 128
    uint4* w4tab = (uint4*)(wsf + 526464); // 2048 uint4 (32 KB)

    setup_kernel<<<3, 256, 0, stream>>>(W3, W4, w3s, w4tab);

    // layer 0
    prep_kernel<<<512, 256, 0, stream>>>(X, w3s, W5, W6, s_ws, Xjf, Xres);
    layer_kernel<true><<<2048, 256, 0, stream>>>(E, s_ws, Xjf, Xres,
        X, Xa, w4tab, eg, ebp, ng, nbp);

    // layer 1 (E output unused by the head -> no E store)
    prep_kernel<<<512, 256, 0, stream>>>(Xa, w3s + 64, W5 + 4096, W6 + 4096,
        s_ws, Xjf, Xres);
    layer_kernel<false><<<2048, 256, 0, stream>>>(E, s_ws, Xjf, Xres,
        Xa, Xb, w4tab + 1024, eg + 64, ebp + 64, ng + 64, nbp + 64);

    head_kernel<<<512, 256, 0, stream>>>(Xb, hw1, hb1, hw2, hb2, outp);
}

// Round 6
// 291.117 us; speedup vs baseline: 1.2896x; 1.0629x over previous
//
#include <hip/hip_runtime.h>
#include <hip/hip_bf16.h>

#define NB 256   // nodes
#define HH 64    // hidden

using short8 = __attribute__((ext_vector_type(8))) short;
using f4     = __attribute__((ext_vector_type(4))) float;

static __device__ __forceinline__ unsigned short f2bfbits(float f) {
    __hip_bfloat16 h = __float2bfloat16(f);
    return __builtin_bit_cast(unsigned short, h);
}
static __device__ __forceinline__ float bfbits2f(unsigned short u) {
    unsigned int x = (unsigned int)u << 16;
    return __builtin_bit_cast(float, x);
}

// split 8 f32 -> hi (RNE bf16) + lo (RNE residual bf16); v ~= hi + lo (~2^-17)
static __device__ __forceinline__ void split8(const float* v, short8& hi, short8& lo) {
    unsigned int hd[4], ld[4];
    #pragma unroll
    for (int j = 0; j < 4; ++j) {
        unsigned short h0 = f2bfbits(v[2*j]);
        unsigned short h1 = f2bfbits(v[2*j+1]);
        hd[j] = ((unsigned int)h1 << 16) | (unsigned int)h0;
        float r0 = v[2*j]   - bfbits2f(h0);
        float r1 = v[2*j+1] - bfbits2f(h1);
        ld[j] = ((unsigned int)f2bfbits(r1) << 16) | (unsigned int)f2bfbits(r0);
    }
    uint4 h4; h4.x = hd[0]; h4.y = hd[1]; h4.z = hd[2]; h4.w = hd[3];
    uint4 l4; l4.x = ld[0]; l4.y = ld[1]; l4.z = ld[2]; l4.w = ld[3];
    hi = __builtin_bit_cast(short8, h4);
    lo = __builtin_bit_cast(short8, l4);
}

// ---- prep: per-row s, Xj (fragment-native), Xres; BUILD blocks also make
//      the W4 fragment tables and colsum(W4[1]) ----
template<bool BUILD>
__global__ __launch_bounds__(256)
void prep_kernel(const float* __restrict__ Xsrc,
                 const float* __restrict__ W3l,
                 const float* __restrict__ W5l,
                 const float* __restrict__ W6l,
                 const float* __restrict__ W4all,   // BUILD only
                 uint4* __restrict__ w4tab,         // BUILD only
                 float* __restrict__ w41cs,         // BUILD only
                 float* __restrict__ s_ws,
                 float* __restrict__ Xjf,
                 float* __restrict__ Xres_ws)
{
    __shared__ float w5s[64*65];
    __shared__ float w6s[64*65];
    __shared__ float csl[4][64];
    __shared__ float cst[64];
    const int t = threadIdx.x;
    const int w = t >> 6, lane = t & 63;

    if (BUILD && blockIdx.x >= 512) {
        // block 512 -> layer-0 table, block 513 -> layer-1 table + colsum(W4[1])
        const int l = blockIdx.x - 512;
        const float* W4l = W4all + (size_t)l * 4096;
        uint4* tab = w4tab + (size_t)l * 1024;
        const int mt = w, m = lane & 15, q = lane >> 4;
        const float* row = W4l + (size_t)(mt*16 + m) * 64;
        #pragma unroll
        for (int ks = 0; ks < 2; ++ks) {
            float v[8];
            *reinterpret_cast<float4*>(&v[0]) = *reinterpret_cast<const float4*>(row + ks*32 + q*8);
            *reinterpret_cast<float4*>(&v[4]) = *reinterpret_cast<const float4*>(row + ks*32 + q*8 + 4);
            short8 hi, lo;
            split8(v, hi, lo);
            tab[(mt*4 + ks)*64 + lane]     = __builtin_bit_cast(uint4, hi);
            tab[(mt*4 + 2 + ks)*64 + lane] = __builtin_bit_cast(uint4, lo);
        }
        if (l == 1) {
            float p = 0.f;
            #pragma unroll
            for (int i = 0; i < 16; ++i) p += W4l[(size_t)(w*16 + i)*64 + lane];
            csl[w][lane] = p;
            __syncthreads();
            if (t < 64) w41cs[t] = (csl[0][t] + csl[1][t]) + (csl[2][t] + csl[3][t]);
        }
        return;
    }

    // stage W5/W6 to LDS + W3 column-sum partials
    #pragma unroll
    for (int jj = 0; jj < 4; ++jj) {
        const int fidx = jj*1024 + t*4;
        float4 v5 = *reinterpret_cast<const float4*>(W5l + fidx);
        float4 v6 = *reinterpret_cast<const float4*>(W6l + fidx);
        const int row = fidx >> 6, col = fidx & 63;
        w5s[row*65+col+0] = v5.x; w5s[row*65+col+1] = v5.y;
        w5s[row*65+col+2] = v5.z; w5s[row*65+col+3] = v5.w;
        w6s[row*65+col+0] = v6.x; w6s[row*65+col+1] = v6.y;
        w6s[row*65+col+2] = v6.z; w6s[row*65+col+3] = v6.w;
    }
    float pcs = 0.f;
    #pragma unroll
    for (int i = 0; i < 16; ++i) pcs += W3l[(size_t)(w*16 + i)*64 + lane];
    csl[w][lane] = pcs;
    __syncthreads();
    if (t < 64) cst[t] = (csl[0][t] + csl[1][t]) + (csl[2][t] + csl[3][t]);
    __syncthreads();

    const int r = blockIdx.x * 4 + w;                 // b*256 + i
    float xr[64];
    #pragma unroll
    for (int k = 0; k < 16; ++k) {
        float4 v = *reinterpret_cast<const float4*>(Xsrc + (size_t)r*64 + k*4);
        xr[k*4+0] = v.x; xr[k*4+1] = v.y; xr[k*4+2] = v.z; xr[k*4+3] = v.w;
    }
    float aj = 0.f, ar = 0.f;
    #pragma unroll
    for (int k = 0; k < 64; ++k) {
        aj += xr[k] * w5s[lane*65 + k];
        ar += xr[k] * w6s[lane*65 + k];
    }
    // Xj in fragment-native layout: [b][wj][jt][mt][q*16+m][ri]
    const int b = r >> 8, j = r & 255;
    const int wj = j >> 6, jt = (j >> 4) & 3, m = j & 15;
    const int mt = lane >> 4, q = (lane >> 2) & 3, ri = lane & 3;
    Xjf[(size_t)b*16384 + (size_t)(((wj*4 + jt)*4 + mt)*64 + (q*16 + m))*4 + ri] = aj;
    Xres_ws[(size_t)r*64 + lane] = ar;
    float sv = xr[lane] * cst[lane];
    #pragma unroll
    for (int d = 1; d < 64; d <<= 1) sv += __shfl_xor(sv, d, 64);
    if (lane == 0) s_ws[r] = sv;
}

// ---- fused layer ----
// One block per (b,i). D[h][j] = sum_c W4[h][c]*E[j][c].
// FIRST: B = raw f32 E rows (16 hoisted dwordx4/wave), split hi/lo, 24 MFMA/jt.
//        Epilogue: LN(E_next) -> single bf16 plane in B-frag layout, in place
//        over slice bytes [0,32K); exact t1 = LNE . colsum(W4[1]) f32 at
//        [32K,33K). All raw reads drain at barriers before these stores.
// !FIRST: B = 8 hoisted dwordx4 frag loads; A = hi-only; logits from stored t1.
// LAST: head fused into wave-0 epilogue (hw1/hw2 LDS-staged); no Xnext store.
template<bool FIRST, bool LAST>
__global__ __launch_bounds__(256)
void layer_kernel(void* Ebuf,
                  const float* __restrict__ s_ws,
                  const float* __restrict__ Xjf,
                  const float* __restrict__ Xres_ws,
                  const float* __restrict__ Xold,
                  float* __restrict__ Xnext,
                  const uint4* __restrict__ w4tab,
                  const float* __restrict__ w41cs,
                  const float* __restrict__ eg,
                  const float* __restrict__ eb,
                  const float* __restrict__ ng,
                  const float* __restrict__ nb,
                  const float* __restrict__ hw1,
                  const float* __restrict__ hb1,
                  const float* __restrict__ hw2,
                  const float* __restrict__ hb2,
                  float* __restrict__ outp)
{
    __shared__ float att[NB];
    __shared__ float red[8];
    __shared__ float agg_lds[4][64];
    __shared__ float w1s[LAST ? 64*65 : 1];
    __shared__ float w2s[LAST ? 10*65 : 1];

    const int bi  = blockIdx.x;          // b*256 + i
    const int b   = bi >> 8;
    const int tid = threadIdx.x;
    const int w   = tid >> 6;            // wave -> j in [w*64, w*64+64)
    const int lane = tid & 63;
    const int m = lane & 15;
    const int q = lane >> 4;

    char* ebase = (char*)Ebuf + (size_t)bi * 65536;

    // ---- hoisted B loads: maximize loads in flight ----
    float4 rawf[FIRST ? 4 : 1][FIRST ? 4 : 1];
    uint4  rawb[FIRST ? 1 : 4][FIRST ? 1 : 2];
    if constexpr (FIRST) {
        #pragma unroll
        for (int jt = 0; jt < 4; ++jt) {
            const float* er = (const float*)ebase + (size_t)(w*64 + jt*16 + m) * 64;
            rawf[jt][0] = *reinterpret_cast<const float4*>(er + q*8);
            rawf[jt][1] = *reinterpret_cast<const float4*>(er + q*8 + 4);
            rawf[jt][2] = *reinterpret_cast<const float4*>(er + 32 + q*8);
            rawf[jt][3] = *reinterpret_cast<const float4*>(er + 32 + q*8 + 4);
        }
    } else {
        #pragma unroll
        for (int jt = 0; jt < 4; ++jt)
            #pragma unroll
            for (int ks = 0; ks < 2; ++ks)
                rawb[jt][ks] = *reinterpret_cast<const uint4*>(
                    ebase + (size_t)(((w*4 + jt)*2 + ks)*64 + lane) * 16);
    }

    // head weight staging (LAST): overlap with K-loop latency
    if constexpr (LAST) {
        #pragma unroll
        for (int jj = 0; jj < 4; ++jj) {
            const int fidx = jj*1024 + tid*4;
            float4 v = *reinterpret_cast<const float4*>(hw1 + fidx);
            const int row = fidx >> 6, col = fidx & 63;
            w1s[row*65+col+0] = v.x; w1s[row*65+col+1] = v.y;
            w1s[row*65+col+2] = v.z; w1s[row*65+col+3] = v.w;
        }
        if (tid < 160) {
            const int fidx = tid*4;
            float4 v = *reinterpret_cast<const float4*>(hw2 + fidx);
            const int row = fidx >> 6, col = fidx & 63;
            w2s[row*65+col+0] = v.x; w2s[row*65+col+1] = v.y;
            w2s[row*65+col+2] = v.z; w2s[row*65+col+3] = v.w;
        }
    }

    // A fragments (hi/lo for FIRST, hi-only for layer 1)
    short8 aH[4][2];
    short8 aL[FIRST ? 4 : 1][FIRST ? 2 : 1];
    #pragma unroll
    for (int mt = 0; mt < 4; ++mt) {
        aH[mt][0] = __builtin_bit_cast(short8, w4tab[(mt*4 + 0)*64 + lane]);
        aH[mt][1] = __builtin_bit_cast(short8, w4tab[(mt*4 + 1)*64 + lane]);
        if constexpr (FIRST) {
            aL[mt][0] = __builtin_bit_cast(short8, w4tab[(mt*4 + 2)*64 + lane]);
            aL[mt][1] = __builtin_bit_cast(short8, w4tab[(mt*4 + 3)*64 + lane]);
        }
    }

    f4 acc[4][4] = {};   // [mt][jt]

    #pragma unroll
    for (int jt = 0; jt < 4; ++jt) {
        if constexpr (FIRST) {
            short8 bh0, bl0, bh1, bl1;
            float v0[8], v1[8];
            *reinterpret_cast<float4*>(&v0[0]) = rawf[jt][0];
            *reinterpret_cast<float4*>(&v0[4]) = rawf[jt][1];
            *reinterpret_cast<float4*>(&v1[0]) = rawf[jt][2];
            *reinterpret_cast<float4*>(&v1[4]) = rawf[jt][3];
            split8(v0, bh0, bl0);
            split8(v1, bh1, bl1);
            #pragma unroll
            for (int mt = 0; mt < 4; ++mt) {
                acc[mt][jt] = __builtin_amdgcn_mfma_f32_16x16x32_bf16(aH[mt][0], bh0, acc[mt][jt], 0, 0, 0);
                acc[mt][jt] = __builtin_amdgcn_mfma_f32_16x16x32_bf16(aL[mt][0], bh0, acc[mt][jt], 0, 0, 0);
                acc[mt][jt] = __builtin_amdgcn_mfma_f32_16x16x32_bf16(aH[mt][0], bl0, acc[mt][jt], 0, 0, 0);
                acc[mt][jt] = __builtin_amdgcn_mfma_f32_16x16x32_bf16(aH[mt][1], bh1, acc[mt][jt], 0, 0, 0);
                acc[mt][jt] = __builtin_amdgcn_mfma_f32_16x16x32_bf16(aL[mt][1], bh1, acc[mt][jt], 0, 0, 0);
                acc[mt][jt] = __builtin_amdgcn_mfma_f32_16x16x32_bf16(aH[mt][1], bl1, acc[mt][jt], 0, 0, 0);
            }
        } else {
            short8 b0 = __builtin_bit_cast(short8, rawb[jt][0]);
            short8 b1 = __builtin_bit_cast(short8, rawb[jt][1]);
            #pragma unroll
            for (int mt = 0; mt < 4; ++mt) {
                acc[mt][jt] = __builtin_amdgcn_mfma_f32_16x16x32_bf16(aH[mt][0], b0, acc[mt][jt], 0, 0, 0);
                acc[mt][jt] = __builtin_amdgcn_mfma_f32_16x16x32_bf16(aH[mt][1], b1, acc[mt][jt], 0, 0, 0);
            }
        }
    }

    // logits
    float lj;
    if constexpr (FIRST) {
        #pragma unroll
        for (int jt = 0; jt < 4; ++jt) {
            float t = 0.f;
            #pragma unroll
            for (int mt = 0; mt < 4; ++mt)
                #pragma unroll
                for (int r = 0; r < 4; ++r) t += acc[mt][jt][r];
            t += __shfl_xor(t, 16, 64);
            t += __shfl_xor(t, 32, 64);
            if (lane < 16) att[w*64 + jt*16 + lane] = t;
        }
        __syncthreads();
        lj = att[tid] + s_ws[bi] + s_ws[b*NB + tid];
    } else {
        const float* t1g = (const float*)(ebase + 32768);
        lj = t1g[tid] + s_ws[bi] + s_ws[b*NB + tid];
    }

    // block softmax over j (tid = j)
    float mx = lj;
    #pragma unroll
    for (int d = 1; d < 64; d <<= 1) mx = fmaxf(mx, __shfl_xor(mx, d, 64));
    if (lane == 0) red[w] = mx;
    __syncthreads();
    mx = fmaxf(fmaxf(red[0], red[1]), fmaxf(red[2], red[3]));
    const float ev = __expf(lj - mx);
    float sm = ev;
    #pragma unroll
    for (int d = 1; d < 64; d <<= 1) sm += __shfl_xor(sm, d, 64);
    if (lane == 0) red[4 + w] = sm;
    __syncthreads();
    sm = (red[4] + red[5]) + (red[6] + red[7]);
    att[tid] = ev / sm;
    __syncthreads();

    // scale E_hat -> E_next
    float attv[4];
    #pragma unroll
    for (int jt = 0; jt < 4; ++jt) attv[jt] = att[w*64 + jt*16 + m];
    #pragma unroll
    for (int mt = 0; mt < 4; ++mt)
        #pragma unroll
        for (int jt = 0; jt < 4; ++jt)
            #pragma unroll
            for (int r = 0; r < 4; ++r) acc[mt][jt][r] *= attv[jt];

    // agg partials: sum_j E_next[j][h]*Xj[b,j,h]  (Xjf fragment-native)
    float p[4][4] = {};
    #pragma unroll
    for (int jt = 0; jt < 4; ++jt) {
        #pragma unroll
        for (int mt = 0; mt < 4; ++mt) {
            float4 xv = *reinterpret_cast<const float4*>(
                Xjf + (size_t)b*16384 + (size_t)(((w*4 + jt)*4 + mt)*64 + lane)*4);
            p[mt][0] += acc[mt][jt][0] * xv.x;
            p[mt][1] += acc[mt][jt][1] * xv.y;
            p[mt][2] += acc[mt][jt][2] * xv.z;
            p[mt][3] += acc[mt][jt][3] * xv.w;
        }
    }
    #pragma unroll
    for (int d = 1; d < 16; d <<= 1)
        #pragma unroll
        for (int mt = 0; mt < 4; ++mt)
            #pragma unroll
            for (int r = 0; r < 4; ++r) p[mt][r] += __shfl_xor(p[mt][r], d, 64);
    if (m == 0) {
        #pragma unroll
        for (int mt = 0; mt < 4; ++mt) {
            float4 st = make_float4(p[mt][0], p[mt][1], p[mt][2], p[mt][3]);
            *reinterpret_cast<float4*>(&agg_lds[w][mt*16 + q*4]) = st;
        }
    }

    // FIRST epilogue: LN stats, bf16 plane store (B-frag layout), exact t1
    if constexpr (FIRST) {
        float mean[4], rstd[4];
        #pragma unroll
        for (int jt = 0; jt < 4; ++jt) {
            float s = 0.f, ss = 0.f;
            #pragma unroll
            for (int mt = 0; mt < 4; ++mt)
                #pragma unroll
                for (int r = 0; r < 4; ++r) { float v = acc[mt][jt][r]; s += v; ss += v*v; }
            s  += __shfl_xor(s, 16, 64);  s  += __shfl_xor(s, 32, 64);
            ss += __shfl_xor(ss, 16, 64); ss += __shfl_xor(ss, 32, 64);
            float mu = s * (1.f/64.f);
            mean[jt] = mu;
            rstd[jt] = rsqrtf(ss * (1.f/64.f) - mu*mu + 1e-5f);
        }
        float egv[4][4], ebv[4][4], wcs[4][4];
        #pragma unroll
        for (int mt = 0; mt < 4; ++mt)
            #pragma unroll
            for (int r = 0; r < 4; ++r) {
                const int c = mt*16 + q*4 + r;
                egv[mt][r] = eg[c];
                ebv[mt][r] = eb[c];
                wcs[mt][r] = w41cs[c];
            }
        float* t1g = (float*)(ebase + 32768);
        float t1p[4] = {0.f, 0.f, 0.f, 0.f};
        #pragma unroll
        for (int jt = 0; jt < 4; ++jt) {
            #pragma unroll
            for (int mt = 0; mt < 4; ++mt) {
                float o[4];
                #pragma unroll
                for (int r = 0; r < 4; ++r) {
                    o[r] = (acc[mt][jt][r] - mean[jt]) * rstd[jt] * egv[mt][r] + ebv[mt][r];
                    t1p[jt] += o[r] * wcs[mt][r];
                }
                uint2 u2;
                u2.x = ((unsigned int)f2bfbits(o[1]) << 16) | (unsigned int)f2bfbits(o[0]);
                u2.y = ((unsigned int)f2bfbits(o[3]) << 16) | (unsigned int)f2bfbits(o[2]);
                const int qp = (2*mt + (q >> 1)) & 3;
                const size_t addr = (size_t)(((w*4 + jt)*2 + (mt >> 1))*64 + qp*16 + m)*16 + (q & 1)*8;
                *reinterpret_cast<uint2*>(ebase + addr) = u2;
            }
        }
        #pragma unroll
        for (int jt = 0; jt < 4; ++jt) {
            float tv = t1p[jt];
            tv += __shfl_xor(tv, 16, 64);
            tv += __shfl_xor(tv, 32, 64);
            if (lane < 16) t1g[w*64 + jt*16 + lane] = tv;
        }
    }
    __syncthreads();

    // X update (wave 0, lane = h) + optional fused head
    if (w == 0) {
        float a = agg_lds[0][lane] + agg_lds[1][lane] + agg_lds[2][lane] + agg_lds[3][lane];
        float v = fmaxf(a + Xres_ws[(size_t)bi*64 + lane], 0.f);
        float s = v, ss = v*v;
        #pragma unroll
        for (int d = 1; d < 64; d <<= 1) { s += __shfl_xor(s, d, 64); ss += __shfl_xor(ss, d, 64); }
        float mu  = s * (1.f/64.f);
        float var = ss * (1.f/64.f) - mu*mu;
        float xfin = (v - mu) * rsqrtf(var + 1e-5f) * ng[lane] + nb[lane] + Xold[(size_t)bi*64 + lane];
        if constexpr (!LAST) {
            Xnext[(size_t)bi*64 + lane] = xfin;
        } else {
            att[lane] = xfin;                    // broadcast X row via LDS
            float h1 = hb1[lane];
            #pragma unroll
            for (int k = 0; k < 64; ++k) h1 += att[k] * w1s[lane*65 + k];
            h1 = fmaxf(h1, 0.f);
            att[64 + lane] = h1;
            if (lane < 10) {
                float o = hb2[lane];
                #pragma unroll
                for (int k = 0; k < 64; ++k) o += att[64 + k] * w2s[lane*65 + k];
                outp[(size_t)bi*10 + lane] = o;
            }
        }
    }
}

extern "C" void kernel_launch(void* const* d_in, const int* in_sizes, int n_in,
                              void* d_out, int out_size, void* d_ws, size_t ws_size,
                              hipStream_t stream) {
    const float* X   = (const float*)d_in[0];
    void*        E   = (void*)d_in[1];           // f32 in; bf16 plane + t1 written in place
    const float* W3  = (const float*)d_in[2];
    const float* W4  = (const float*)d_in[3];
    const float* W5  = (const float*)d_in[4];
    const float* W6  = (const float*)d_in[5];
    const float* ng  = (const float*)d_in[6];
    const float* nbp = (const float*)d_in[7];
    const float* eg  = (const float*)d_in[8];
    const float* ebp = (const float*)d_in[9];
    const float* hw1 = (const float*)d_in[10];
    const float* hb1 = (const float*)d_in[11];
    const float* hw2 = (const float*)d_in[12];
    const float* hb2 = (const float*)d_in[13];
    float* outp = (float*)d_out;

    float* wsf   = (float*)d_ws;
    float* s_ws  = wsf;                    // 2048
    float* Xjf   = wsf + 2048;             // 131072
    float* Xres  = wsf + 133120;           // 131072
    float* Xa    = wsf + 264192;           // 131072
    float* w41cs = wsf + 395264;           // 64
    uint4* w4tab = (uint4*)(wsf + 395392); // 2048 uint4 (32 KB)

    // layer 0 (blocks 512/513 of prep build the W4 tables + colsum(W4[1]))
    prep_kernel<true><<<514, 256, 0, stream>>>(X, W3, W5, W6, W4, w4tab, w41cs,
        s_ws, Xjf, Xres);
    layer_kernel<true, false><<<2048, 256, 0, stream>>>(E, s_ws, Xjf, Xres,
        X, Xa, w4tab, w41cs, eg, ebp, ng, nbp,
        nullptr, nullptr, nullptr, nullptr, nullptr);

    // layer 1 + fused head
    prep_kernel<false><<<512, 256, 0, stream>>>(Xa, W3 + 4096, W5 + 4096, W6 + 4096,
        nullptr, nullptr, nullptr, s_ws, Xjf, Xres);
    layer_kernel<false, true><<<2048, 256, 0, stream>>>(E, s_ws, Xjf, Xres,
        Xa, nullptr, w4tab + 1024, nullptr, nullptr, nullptr, ng + 64, nbp + 64,
        hw1, hb1, hw2, hb2, outp);
}

// Round 7
// 283.353 us; speedup vs baseline: 1.3250x; 1.0274x over previous
//
#include <hip/hip_runtime.h>
#include <hip/hip_bf16.h>

#define NB 256   // nodes
#define HH 64    // hidden

using short8 = __attribute__((ext_vector_type(8))) short;
using f4     = __attribute__((ext_vector_type(4))) float;

static __device__ __forceinline__ unsigned short f2bfbits(float f) {
    __hip_bfloat16 h = __float2bfloat16(f);
    return __builtin_bit_cast(unsigned short, h);
}
static __device__ __forceinline__ float bfbits2f(unsigned short u) {
    unsigned int x = (unsigned int)u << 16;
    return __builtin_bit_cast(float, x);
}

// split 8 f32 -> hi (RNE bf16) + lo (RNE residual bf16); v ~= hi + lo (~2^-17)
static __device__ __forceinline__ void split8(const float* v, short8& hi, short8& lo) {
    unsigned int hd[4], ld[4];
    #pragma unroll
    for (int j = 0; j < 4; ++j) {
        unsigned short h0 = f2bfbits(v[2*j]);
        unsigned short h1 = f2bfbits(v[2*j+1]);
        hd[j] = ((unsigned int)h1 << 16) | (unsigned int)h0;
        float r0 = v[2*j]   - bfbits2f(h0);
        float r1 = v[2*j+1] - bfbits2f(h1);
        ld[j] = ((unsigned int)f2bfbits(r1) << 16) | (unsigned int)f2bfbits(r0);
    }
    uint4 h4; h4.x = hd[0]; h4.y = hd[1]; h4.z = hd[2]; h4.w = hd[3];
    uint4 l4; l4.x = ld[0]; l4.y = ld[1]; l4.z = ld[2]; l4.w = ld[3];
    hi = __builtin_bit_cast(short8, h4);
    lo = __builtin_bit_cast(short8, l4);
}

// ---- prep: per-row s, Xj (fragment-native), Xres; BUILD blocks also make
//      the W4 fragment tables and colsum(W4[1]) ----
template<bool BUILD>
__global__ __launch_bounds__(256)
void prep_kernel(const float* __restrict__ Xsrc,
                 const float* __restrict__ W3l,
                 const float* __restrict__ W5l,
                 const float* __restrict__ W6l,
                 const float* __restrict__ W4all,   // BUILD only
                 uint4* __restrict__ w4tab,         // BUILD only
                 float* __restrict__ w41cs,         // BUILD only
                 float* __restrict__ s_ws,
                 float* __restrict__ Xjf,
                 float* __restrict__ Xres_ws)
{
    __shared__ float w5s[64*65];
    __shared__ float w6s[64*65];
    __shared__ float csl[4][64];
    __shared__ float cst[64];
    const int t = threadIdx.x;
    const int w = t >> 6, lane = t & 63;

    if (BUILD && blockIdx.x >= 512) {
        const int l = blockIdx.x - 512;
        const float* W4l = W4all + (size_t)l * 4096;
        uint4* tab = w4tab + (size_t)l * 1024;
        const int mt = w, m = lane & 15, q = lane >> 4;
        const float* row = W4l + (size_t)(mt*16 + m) * 64;
        #pragma unroll
        for (int ks = 0; ks < 2; ++ks) {
            float v[8];
            *reinterpret_cast<float4*>(&v[0]) = *reinterpret_cast<const float4*>(row + ks*32 + q*8);
            *reinterpret_cast<float4*>(&v[4]) = *reinterpret_cast<const float4*>(row + ks*32 + q*8 + 4);
            short8 hi, lo;
            split8(v, hi, lo);
            tab[(mt*4 + ks)*64 + lane]     = __builtin_bit_cast(uint4, hi);
            tab[(mt*4 + 2 + ks)*64 + lane] = __builtin_bit_cast(uint4, lo);
        }
        if (l == 1) {
            float p = 0.f;
            #pragma unroll
            for (int i = 0; i < 16; ++i) p += W4l[(size_t)(w*16 + i)*64 + lane];
            csl[w][lane] = p;
            __syncthreads();
            if (t < 64) w41cs[t] = (csl[0][t] + csl[1][t]) + (csl[2][t] + csl[3][t]);
        }
        return;
    }

    #pragma unroll
    for (int jj = 0; jj < 4; ++jj) {
        const int fidx = jj*1024 + t*4;
        float4 v5 = *reinterpret_cast<const float4*>(W5l + fidx);
        float4 v6 = *reinterpret_cast<const float4*>(W6l + fidx);
        const int row = fidx >> 6, col = fidx & 63;
        w5s[row*65+col+0] = v5.x; w5s[row*65+col+1] = v5.y;
        w5s[row*65+col+2] = v5.z; w5s[row*65+col+3] = v5.w;
        w6s[row*65+col+0] = v6.x; w6s[row*65+col+1] = v6.y;
        w6s[row*65+col+2] = v6.z; w6s[row*65+col+3] = v6.w;
    }
    float pcs = 0.f;
    #pragma unroll
    for (int i = 0; i < 16; ++i) pcs += W3l[(size_t)(w*16 + i)*64 + lane];
    csl[w][lane] = pcs;
    __syncthreads();
    if (t < 64) cst[t] = (csl[0][t] + csl[1][t]) + (csl[2][t] + csl[3][t]);
    __syncthreads();

    const int r = blockIdx.x * 4 + w;                 // b*256 + i
    float xr[64];
    #pragma unroll
    for (int k = 0; k < 16; ++k) {
        float4 v = *reinterpret_cast<const float4*>(Xsrc + (size_t)r*64 + k*4);
        xr[k*4+0] = v.x; xr[k*4+1] = v.y; xr[k*4+2] = v.z; xr[k*4+3] = v.w;
    }
    float aj = 0.f, ar = 0.f;
    #pragma unroll
    for (int k = 0; k < 64; ++k) {
        aj += xr[k] * w5s[lane*65 + k];
        ar += xr[k] * w6s[lane*65 + k];
    }
    // Xj in fragment-native layout: [b][tj=j>>4][mt][q*16+m][ri]
    const int b = r >> 8, j = r & 255;
    const int wj = j >> 6, jt = (j >> 4) & 3, m = j & 15;
    const int mt = lane >> 4, q = (lane >> 2) & 3, ri = lane & 3;
    Xjf[(size_t)b*16384 + (size_t)(((wj*4 + jt)*4 + mt)*64 + (q*16 + m))*4 + ri] = aj;
    Xres_ws[(size_t)r*64 + lane] = ar;
    float sv = xr[lane] * cst[lane];
    #pragma unroll
    for (int d = 1; d < 64; d <<= 1) sv += __shfl_xor(sv, d, 64);
    if (lane == 0) s_ws[r] = sv;
}

// ---- layer 0: 4-wave cooperative block per (b,i) (unchanged from round 6) ----
__global__ __launch_bounds__(256)
void layer0_kernel(void* Ebuf,
                   const float* __restrict__ s_ws,
                   const float* __restrict__ Xjf,
                   const float* __restrict__ Xres_ws,
                   const float* __restrict__ Xold,
                   float* __restrict__ Xnext,
                   const uint4* __restrict__ w4tab,
                   const float* __restrict__ w41cs,
                   const float* __restrict__ eg,
                   const float* __restrict__ eb,
                   const float* __restrict__ ng,
                   const float* __restrict__ nb)
{
    __shared__ float att[NB];
    __shared__ float red[8];
    __shared__ float agg_lds[4][64];

    const int bi  = blockIdx.x;
    const int b   = bi >> 8;
    const int tid = threadIdx.x;
    const int w   = tid >> 6;
    const int lane = tid & 63;
    const int m = lane & 15;
    const int q = lane >> 4;

    char* ebase = (char*)Ebuf + (size_t)bi * 65536;

    float4 rawf[4][4];
    #pragma unroll
    for (int jt = 0; jt < 4; ++jt) {
        const float* er = (const float*)ebase + (size_t)(w*64 + jt*16 + m) * 64;
        rawf[jt][0] = *reinterpret_cast<const float4*>(er + q*8);
        rawf[jt][1] = *reinterpret_cast<const float4*>(er + q*8 + 4);
        rawf[jt][2] = *reinterpret_cast<const float4*>(er + 32 + q*8);
        rawf[jt][3] = *reinterpret_cast<const float4*>(er + 32 + q*8 + 4);
    }

    short8 aH[4][2], aL[4][2];
    #pragma unroll
    for (int mt = 0; mt < 4; ++mt) {
        aH[mt][0] = __builtin_bit_cast(short8, w4tab[(mt*4 + 0)*64 + lane]);
        aH[mt][1] = __builtin_bit_cast(short8, w4tab[(mt*4 + 1)*64 + lane]);
        aL[mt][0] = __builtin_bit_cast(short8, w4tab[(mt*4 + 2)*64 + lane]);
        aL[mt][1] = __builtin_bit_cast(short8, w4tab[(mt*4 + 3)*64 + lane]);
    }

    f4 acc[4][4] = {};

    #pragma unroll
    for (int jt = 0; jt < 4; ++jt) {
        short8 bh0, bl0, bh1, bl1;
        float v0[8], v1[8];
        *reinterpret_cast<float4*>(&v0[0]) = rawf[jt][0];
        *reinterpret_cast<float4*>(&v0[4]) = rawf[jt][1];
        *reinterpret_cast<float4*>(&v1[0]) = rawf[jt][2];
        *reinterpret_cast<float4*>(&v1[4]) = rawf[jt][3];
        split8(v0, bh0, bl0);
        split8(v1, bh1, bl1);
        #pragma unroll
        for (int mt = 0; mt < 4; ++mt) {
            acc[mt][jt] = __builtin_amdgcn_mfma_f32_16x16x32_bf16(aH[mt][0], bh0, acc[mt][jt], 0, 0, 0);
            acc[mt][jt] = __builtin_amdgcn_mfma_f32_16x16x32_bf16(aL[mt][0], bh0, acc[mt][jt], 0, 0, 0);
            acc[mt][jt] = __builtin_amdgcn_mfma_f32_16x16x32_bf16(aH[mt][0], bl0, acc[mt][jt], 0, 0, 0);
            acc[mt][jt] = __builtin_amdgcn_mfma_f32_16x16x32_bf16(aH[mt][1], bh1, acc[mt][jt], 0, 0, 0);
            acc[mt][jt] = __builtin_amdgcn_mfma_f32_16x16x32_bf16(aL[mt][1], bh1, acc[mt][jt], 0, 0, 0);
            acc[mt][jt] = __builtin_amdgcn_mfma_f32_16x16x32_bf16(aH[mt][1], bl1, acc[mt][jt], 0, 0, 0);
        }
    }

    #pragma unroll
    for (int jt = 0; jt < 4; ++jt) {
        float t = 0.f;
        #pragma unroll
        for (int mt = 0; mt < 4; ++mt)
            #pragma unroll
            for (int r = 0; r < 4; ++r) t += acc[mt][jt][r];
        t += __shfl_xor(t, 16, 64);
        t += __shfl_xor(t, 32, 64);
        if (lane < 16) att[w*64 + jt*16 + lane] = t;
    }
    __syncthreads();

    float lj = att[tid] + s_ws[bi] + s_ws[b*NB + tid];
    float mx = lj;
    #pragma unroll
    for (int d = 1; d < 64; d <<= 1) mx = fmaxf(mx, __shfl_xor(mx, d, 64));
    if (lane == 0) red[w] = mx;
    __syncthreads();
    mx = fmaxf(fmaxf(red[0], red[1]), fmaxf(red[2], red[3]));
    const float ev = __expf(lj - mx);
    float sm = ev;
    #pragma unroll
    for (int d = 1; d < 64; d <<= 1) sm += __shfl_xor(sm, d, 64);
    if (lane == 0) red[4 + w] = sm;
    __syncthreads();
    sm = (red[4] + red[5]) + (red[6] + red[7]);
    att[tid] = ev / sm;
    __syncthreads();

    float attv[4];
    #pragma unroll
    for (int jt = 0; jt < 4; ++jt) attv[jt] = att[w*64 + jt*16 + m];
    #pragma unroll
    for (int mt = 0; mt < 4; ++mt)
        #pragma unroll
        for (int jt = 0; jt < 4; ++jt)
            #pragma unroll
            for (int r = 0; r < 4; ++r) acc[mt][jt][r] *= attv[jt];

    float p[4][4] = {};
    #pragma unroll
    for (int jt = 0; jt < 4; ++jt) {
        #pragma unroll
        for (int mt = 0; mt < 4; ++mt) {
            float4 xv = *reinterpret_cast<const float4*>(
                Xjf + (size_t)b*16384 + (size_t)(((w*4 + jt)*4 + mt)*64 + lane)*4);
            p[mt][0] += acc[mt][jt][0] * xv.x;
            p[mt][1] += acc[mt][jt][1] * xv.y;
            p[mt][2] += acc[mt][jt][2] * xv.z;
            p[mt][3] += acc[mt][jt][3] * xv.w;
        }
    }
    #pragma unroll
    for (int d = 1; d < 16; d <<= 1)
        #pragma unroll
        for (int mt = 0; mt < 4; ++mt)
            #pragma unroll
            for (int r = 0; r < 4; ++r) p[mt][r] += __shfl_xor(p[mt][r], d, 64);
    if (m == 0) {
        #pragma unroll
        for (int mt = 0; mt < 4; ++mt) {
            float4 st = make_float4(p[mt][0], p[mt][1], p[mt][2], p[mt][3]);
            *reinterpret_cast<float4*>(&agg_lds[w][mt*16 + q*4]) = st;
        }
    }

    // LN stats + bf16 plane store (B-frag layout) + exact t1
    {
        float mean[4], rstd[4];
        #pragma unroll
        for (int jt = 0; jt < 4; ++jt) {
            float s = 0.f, ss = 0.f;
            #pragma unroll
            for (int mt = 0; mt < 4; ++mt)
                #pragma unroll
                for (int r = 0; r < 4; ++r) { float v = acc[mt][jt][r]; s += v; ss += v*v; }
            s  += __shfl_xor(s, 16, 64);  s  += __shfl_xor(s, 32, 64);
            ss += __shfl_xor(ss, 16, 64); ss += __shfl_xor(ss, 32, 64);
            float mu = s * (1.f/64.f);
            mean[jt] = mu;
            rstd[jt] = rsqrtf(ss * (1.f/64.f) - mu*mu + 1e-5f);
        }
        float egv[4][4], ebv[4][4], wcs[4][4];
        #pragma unroll
        for (int mt = 0; mt < 4; ++mt)
            #pragma unroll
            for (int r = 0; r < 4; ++r) {
                const int c = mt*16 + q*4 + r;
                egv[mt][r] = eg[c];
                ebv[mt][r] = eb[c];
                wcs[mt][r] = w41cs[c];
            }
        float* t1g = (float*)(ebase + 32768);
        float t1p[4] = {0.f, 0.f, 0.f, 0.f};
        #pragma unroll
        for (int jt = 0; jt < 4; ++jt) {
            #pragma unroll
            for (int mt = 0; mt < 4; ++mt) {
                float o[4];
                #pragma unroll
                for (int r = 0; r < 4; ++r) {
                    o[r] = (acc[mt][jt][r] - mean[jt]) * rstd[jt] * egv[mt][r] + ebv[mt][r];
                    t1p[jt] += o[r] * wcs[mt][r];
                }
                uint2 u2;
                u2.x = ((unsigned int)f2bfbits(o[1]) << 16) | (unsigned int)f2bfbits(o[0]);
                u2.y = ((unsigned int)f2bfbits(o[3]) << 16) | (unsigned int)f2bfbits(o[2]);
                const int qp = (2*mt + (q >> 1)) & 3;
                const size_t addr = (size_t)(((w*4 + jt)*2 + (mt >> 1))*64 + qp*16 + m)*16 + (q & 1)*8;
                *reinterpret_cast<uint2*>(ebase + addr) = u2;
            }
        }
        #pragma unroll
        for (int jt = 0; jt < 4; ++jt) {
            float tv = t1p[jt];
            tv += __shfl_xor(tv, 16, 64);
            tv += __shfl_xor(tv, 32, 64);
            if (lane < 16) t1g[w*64 + jt*16 + lane] = tv;
        }
    }
    __syncthreads();

    if (w == 0) {
        float a = agg_lds[0][lane] + agg_lds[1][lane] + agg_lds[2][lane] + agg_lds[3][lane];
        float v = fmaxf(a + Xres_ws[(size_t)bi*64 + lane], 0.f);
        float s = v, ss = v*v;
        #pragma unroll
        for (int d = 1; d < 64; d <<= 1) { s += __shfl_xor(s, d, 64); ss += __shfl_xor(ss, d, 64); }
        float mu  = s * (1.f/64.f);
        float var = ss * (1.f/64.f) - mu*mu;
        Xnext[(size_t)bi*64 + lane] =
            (v - mu) * rsqrtf(var + 1e-5f) * ng[lane] + nb[lane] + Xold[(size_t)bi*64 + lane];
    }
}

// ---- layer 1 + head: barrier-free, ONE WAVE per (b,i) ----
// Block = 4 independent waves (bi = blockIdx*4 + wave). Single barrier at
// start (head-weight LDS staging). Softmax from precomputed t1 (in-register,
// shuffles only); j streamed in 4 chunks of 64; agg butterfly-reduced;
// per-wave X-update + fused 2-layer head.
__global__ __launch_bounds__(256)
void layer1_kernel(const void* __restrict__ Ebuf,
                   const float* __restrict__ s_ws,
                   const float* __restrict__ Xjf,
                   const float* __restrict__ Xres_ws,
                   const float* __restrict__ Xold,
                   const uint4* __restrict__ w4tab,
                   const float* __restrict__ ng,
                   const float* __restrict__ nb,
                   const float* __restrict__ hw1,
                   const float* __restrict__ hb1,
                   const float* __restrict__ hw2,
                   const float* __restrict__ hb2,
                   float* __restrict__ outp)
{
    __shared__ float w1s[64*65];
    __shared__ float w2s[10*65];

    const int tid = threadIdx.x;
    const int w = tid >> 6, lane = tid & 63;
    const int m = lane & 15, q = lane >> 4;

    // stage head weights (one barrier, then waves run free)
    #pragma unroll
    for (int jj = 0; jj < 4; ++jj) {
        const int fidx = jj*1024 + tid*4;
        float4 v = *reinterpret_cast<const float4*>(hw1 + fidx);
        const int row = fidx >> 6, col = fidx & 63;
        w1s[row*65+col+0] = v.x; w1s[row*65+col+1] = v.y;
        w1s[row*65+col+2] = v.z; w1s[row*65+col+3] = v.w;
    }
    if (tid < 160) {
        const int fidx = tid*4;
        float4 v = *reinterpret_cast<const float4*>(hw2 + fidx);
        const int row = fidx >> 6, col = fidx & 63;
        w2s[row*65+col+0] = v.x; w2s[row*65+col+1] = v.y;
        w2s[row*65+col+2] = v.z; w2s[row*65+col+3] = v.w;
    }
    __syncthreads();

    const int bi = blockIdx.x * 4 + w;     // b*256 + i
    const int b  = bi >> 8;
    const char* ebase = (const char*)Ebuf + (size_t)bi * 65536;
    const float* t1g = (const float*)(ebase + 32768);

    // ---- softmax from precomputed t1 (pure wave ops) ----
    float l[4];
    const float si = s_ws[bi];
    #pragma unroll
    for (int c = 0; c < 4; ++c)
        l[c] = t1g[c*64 + lane] + si + s_ws[b*NB + c*64 + lane];
    float mx = fmaxf(fmaxf(l[0], l[1]), fmaxf(l[2], l[3]));
    #pragma unroll
    for (int d = 1; d < 64; d <<= 1) mx = fmaxf(mx, __shfl_xor(mx, d, 64));
    float sme = 0.f;
    #pragma unroll
    for (int c = 0; c < 4; ++c) { l[c] = __expf(l[c] - mx); sme += l[c]; }
    #pragma unroll
    for (int d = 1; d < 64; d <<= 1) sme += __shfl_xor(sme, d, 64);
    const float inv = 1.f / sme;
    #pragma unroll
    for (int c = 0; c < 4; ++c) l[c] *= inv;   // att for j = c*64 + lane

    // A fragments (hi-only), L2-hot
    short8 aH[4][2];
    #pragma unroll
    for (int mt = 0; mt < 4; ++mt) {
        aH[mt][0] = __builtin_bit_cast(short8, w4tab[(mt*4 + 0)*64 + lane]);
        aH[mt][1] = __builtin_bit_cast(short8, w4tab[(mt*4 + 1)*64 + lane]);
    }

    // ---- stream j in 4 chunks of 64 ----
    float p[4][4] = {};
    #pragma unroll
    for (int c = 0; c < 4; ++c) {
        uint4 rb[4][2];
        #pragma unroll
        for (int jt = 0; jt < 4; ++jt)
            #pragma unroll
            for (int ks = 0; ks < 2; ++ks)
                rb[jt][ks] = *reinterpret_cast<const uint4*>(
                    ebase + (size_t)(((c*4 + jt)*2 + ks)*64 + lane) * 16);
        #pragma unroll
        for (int jt = 0; jt < 4; ++jt) {
            short8 b0 = __builtin_bit_cast(short8, rb[jt][0]);
            short8 b1 = __builtin_bit_cast(short8, rb[jt][1]);
            f4 a0 = {}, a1 = {}, a2 = {}, a3 = {};
            a0 = __builtin_amdgcn_mfma_f32_16x16x32_bf16(aH[0][0], b0, a0, 0, 0, 0);
            a0 = __builtin_amdgcn_mfma_f32_16x16x32_bf16(aH[0][1], b1, a0, 0, 0, 0);
            a1 = __builtin_amdgcn_mfma_f32_16x16x32_bf16(aH[1][0], b0, a1, 0, 0, 0);
            a1 = __builtin_amdgcn_mfma_f32_16x16x32_bf16(aH[1][1], b1, a1, 0, 0, 0);
            a2 = __builtin_amdgcn_mfma_f32_16x16x32_bf16(aH[2][0], b0, a2, 0, 0, 0);
            a2 = __builtin_amdgcn_mfma_f32_16x16x32_bf16(aH[2][1], b1, a2, 0, 0, 0);
            a3 = __builtin_amdgcn_mfma_f32_16x16x32_bf16(aH[3][0], b0, a3, 0, 0, 0);
            a3 = __builtin_amdgcn_mfma_f32_16x16x32_bf16(aH[3][1], b1, a3, 0, 0, 0);
            const float av = __shfl(l[c], jt*16 + m, 64);
            const float* xb = Xjf + (size_t)b*16384 + (size_t)(((c*4 + jt)*4)*64 + lane)*4;
            float4 x0 = *reinterpret_cast<const float4*>(xb);
            float4 x1 = *reinterpret_cast<const float4*>(xb + 256);
            float4 x2 = *reinterpret_cast<const float4*>(xb + 512);
            float4 x3 = *reinterpret_cast<const float4*>(xb + 768);
            p[0][0] += a0[0]*av*x0.x; p[0][1] += a0[1]*av*x0.y;
            p[0][2] += a0[2]*av*x0.z; p[0][3] += a0[3]*av*x0.w;
            p[1][0] += a1[0]*av*x1.x; p[1][1] += a1[1]*av*x1.y;
            p[1][2] += a1[2]*av*x1.z; p[1][3] += a1[3]*av*x1.w;
            p[2][0] += a2[0]*av*x2.x; p[2][1] += a2[1]*av*x2.y;
            p[2][2] += a2[2]*av*x2.z; p[2][3] += a2[3]*av*x2.w;
            p[3][0] += a3[0]*av*x3.x; p[3][1] += a3[1]*av*x3.y;
            p[3][2] += a3[2]*av*x3.z; p[3][3] += a3[3]*av*x3.w;
        }
    }

    // butterfly-reduce over the 16 m-lanes: all lanes end with agg for
    // h = mt*16 + q*4 + r (q = lane>>4)
    #pragma unroll
    for (int d = 1; d < 16; d <<= 1)
        #pragma unroll
        for (int mt = 0; mt < 4; ++mt)
            #pragma unroll
            for (int r = 0; r < 4; ++r) p[mt][r] += __shfl_xor(p[mt][r], d, 64);

    // per-wave X-update: v = relu(agg + Xres), LN over h, + Xold
    float4 xres[4], xold[4], ngv[4], nbv[4];
    #pragma unroll
    for (int mt = 0; mt < 4; ++mt) {
        const int hb = mt*16 + q*4;
        xres[mt] = *reinterpret_cast<const float4*>(Xres_ws + (size_t)bi*64 + hb);
        xold[mt] = *reinterpret_cast<const float4*>(Xold    + (size_t)bi*64 + hb);
        ngv[mt]  = *reinterpret_cast<const float4*>(ng + hb);
        nbv[mt]  = *reinterpret_cast<const float4*>(nb + hb);
    }
    float v[4][4];
    float s = 0.f, ss = 0.f;
    #pragma unroll
    for (int mt = 0; mt < 4; ++mt) {
        v[mt][0] = fmaxf(p[mt][0] + xres[mt].x, 0.f);
        v[mt][1] = fmaxf(p[mt][1] + xres[mt].y, 0.f);
        v[mt][2] = fmaxf(p[mt][2] + xres[mt].z, 0.f);
        v[mt][3] = fmaxf(p[mt][3] + xres[mt].w, 0.f);
        #pragma unroll
        for (int r = 0; r < 4; ++r) { s += v[mt][r]; ss += v[mt][r]*v[mt][r]; }
    }
    s  += __shfl_xor(s, 16, 64);  s  += __shfl_xor(s, 32, 64);
    ss += __shfl_xor(ss, 16, 64); ss += __shfl_xor(ss, 32, 64);
    const float mu   = s * (1.f/64.f);
    const float rstd = rsqrtf(ss * (1.f/64.f) - mu*mu + 1e-5f);
    float xf[4][4];
    #pragma unroll
    for (int mt = 0; mt < 4; ++mt) {
        xf[mt][0] = (v[mt][0] - mu) * rstd * ngv[mt].x + nbv[mt].x + xold[mt].x;
        xf[mt][1] = (v[mt][1] - mu) * rstd * ngv[mt].y + nbv[mt].y + xold[mt].y;
        xf[mt][2] = (v[mt][2] - mu) * rstd * ngv[mt].z + nbv[mt].z + xold[mt].z;
        xf[mt][3] = (v[mt][3] - mu) * rstd * ngv[mt].w + nbv[mt].w + xold[mt].w;
    }

    // ---- fused head (per-wave, X broadcast via shuffles) ----
    float h1 = hb1[lane];
    #pragma unroll
    for (int mt = 0; mt < 4; ++mt)
        #pragma unroll
        for (int q2 = 0; q2 < 4; ++q2)
            #pragma unroll
            for (int r = 0; r < 4; ++r) {
                const float xv = __shfl(xf[mt][r], q2*16, 64);
                h1 += xv * w1s[lane*65 + mt*16 + q2*4 + r];
            }
    h1 = fmaxf(h1, 0.f);
    float pa[10];
    #pragma unroll
    for (int a = 0; a < 10; ++a) pa[a] = h1 * w2s[a*65 + lane];
    #pragma unroll
    for (int d = 1; d < 64; d <<= 1)
        #pragma unroll
        for (int a = 0; a < 10; ++a) pa[a] += __shfl_xor(pa[a], d, 64);
    if (lane == 0) {
        #pragma unroll
        for (int a = 0; a < 10; ++a) outp[(size_t)bi*10 + a] = pa[a];
    }
}

extern "C" void kernel_launch(void* const* d_in, const int* in_sizes, int n_in,
                              void* d_out, int out_size, void* d_ws, size_t ws_size,
                              hipStream_t stream) {
    const float* X   = (const float*)d_in[0];
    void*        E   = (void*)d_in[1];           // f32 in; bf16 plane + t1 written in place
    const float* W3  = (const float*)d_in[2];
    const float* W4  = (const float*)d_in[3];
    const float* W5  = (const float*)d_in[4];
    const float* W6  = (const float*)d_in[5];
    const float* ng  = (const float*)d_in[6];
    const float* nbp = (const float*)d_in[7];
    const float* eg  = (const float*)d_in[8];
    const float* ebp = (const float*)d_in[9];
    const float* hw1 = (const float*)d_in[10];
    const float* hb1 = (const float*)d_in[11];
    const float* hw2 = (const float*)d_in[12];
    const float* hb2 = (const float*)d_in[13];
    float* outp = (float*)d_out;

    float* wsf   = (float*)d_ws;
    float* s_ws  = wsf;                    // 2048
    float* Xjf   = wsf + 2048;             // 131072
    float* Xres  = wsf + 133120;           // 131072
    float* Xa    = wsf + 264192;           // 131072
    float* w41cs = wsf + 395264;           // 64
    uint4* w4tab = (uint4*)(wsf + 395392); // 2048 uint4 (32 KB)

    // layer 0 (blocks 512/513 of prep build the W4 tables + colsum(W4[1]))
    prep_kernel<true><<<514, 256, 0, stream>>>(X, W3, W5, W6, W4, w4tab, w41cs,
        s_ws, Xjf, Xres);
    layer0_kernel<<<2048, 256, 0, stream>>>(E, s_ws, Xjf, Xres,
        X, Xa, w4tab, w41cs, eg, ebp, ng, nbp);

    // layer 1 + fused head (barrier-free per-wave)
    prep_kernel<false><<<512, 256, 0, stream>>>(Xa, W3 + 4096, W5 + 4096, W6 + 4096,
        nullptr, nullptr, nullptr, s_ws, Xjf, Xres);
    layer1_kernel<<<512, 256, 0, stream>>>(E, s_ws, Xjf, Xres,
        Xa, w4tab + 1024, ng + 64, nbp + 64, hw1, hb1, hw2, hb2, outp);
}